// Round 3
// baseline (132.895 us; speedup 1.0000x reference)
//
#include <hip/hip_runtime.h>

// Depthwise cross-correlation: z (64,256,7,7) over x (64,256,31,31) VALID
// -> out (64,256,25,25), scaled 0.001.
//
// Round 3: round-2 was latency-bound (23 KB LDS -> 6 blocks/CU, 12 waves,
// ds_read2->FMA chains unhidden). Fix: bf16 LDS staging (11 KB/block) +
// thread = (slice, out-row) computing a full 25-wide row:
//  - per kernel row, read the whole 31-el x row as 16 aligned dwords
//    (8x ds_read2_b32, base always even: row stride 34 els), unpack by shift
//  - 175 independent FMAs per LDS round-trip (latency hidden by ILP)
//  - z packed 2-per-dword in LDS, unpacked per weight (compile-time parity)
//  - stores: 100 B contiguous per lane
// Bank math: read base dword (15*sl + 17*row) mod 32, 17 coprime 32 -> <=2-way (free).

#define KH 7
#define KW 7
#define XH 31
#define XW 31
#define OH 25
#define OW 25
#define NSLICE (64 * 256)
#define SPB 5
#define THREADS 128
#define SEL 34                    // bf16 elements per padded LDS row (even!)
#define XSLICE_E (XH * SEL)       // 1054 bf16 els per slice
#define XSLICE_W (XSLICE_E / 2)   // 527 dwords per slice
#define ROW_W (SEL / 2)           // 17 dwords per row

__global__ __launch_bounds__(THREADS)
void xcorr_dw_kernel(const float* __restrict__ z,
                     const float* __restrict__ x,
                     float* __restrict__ out) {
    const int tid = threadIdx.x;
    const int base_slice = blockIdx.x * SPB;
    const int nsl = min(SPB, NSLICE - base_slice);

    __shared__ unsigned short xs[SPB * XSLICE_E];   // 10540 B
    __shared__ unsigned int   z_pk[SPB * 25];       // 500 B (49 bf16 + pad per slice)

    const float* __restrict__ xg = x + (size_t)base_slice * (XH * XW);
    const float* __restrict__ zg = z + (size_t)base_slice * (KH * KW);

    // ---- Stage x as bf16 (round-half-up): el = idx + 3*(idx/31) maps the
    // compact global layout onto row stride 34 (continuous across slices:
    // 31*34 = 1054). Writes hit (el>>1) mod 32 -> ~2 lanes/bank (free).
    const int nx = nsl * (XH * XW);
    for (int idx = tid; idx < nx; idx += THREADS) {
        const int row = idx / XW;                 // magic-mul div by 31
        const int el  = idx + 3 * row;
        const unsigned int u = __float_as_uint(xg[idx]);
        xs[el] = (unsigned short)((u + 0x8000u) >> 16);
    }
    // ---- Stage z packed: dword t holds bf16(z[2k]),bf16(z[2k+1]) for
    // slice sl=t/25, k=t%25; global index g = 49*sl + 2*k = 2*t - sl.
    if (tid < SPB * 25) {
        const int sl = tid / 25;
        const int k  = tid - sl * 25;
        if (sl < nsl) {
            const int g = 2 * tid - sl;
            const unsigned int ua = __float_as_uint(zg[g]);
            const unsigned int ub = (k < 24) ? __float_as_uint(zg[g + 1]) : 0u;
            z_pk[tid] = (((ub + 0x8000u) >> 16) << 16) | ((ua + 0x8000u) >> 16);
        }
    }
    __syncthreads();

    // ---- Compute: thread -> (slice, output row). 125 active lanes.
    const int sl = tid / 25;          // 0..5
    const int oy = tid - sl * 25;     // output row 0..24
    if (sl < nsl) {
        // z dwords into registers (broadcast-ish LDS reads, 13x read2).
        unsigned int zp[25];
        #pragma unroll
        for (int k = 0; k < 25; ++k) zp[k] = z_pk[sl * 25 + k];

        const unsigned int* __restrict__ xw =
            (const unsigned int*)xs + sl * XSLICE_W;

        float acc[OW] = {};
        #pragma unroll
        for (int i = 0; i < KH; ++i) {
            const unsigned int* __restrict__ rw = xw + (oy + i) * ROW_W;
            unsigned int r[16];
            #pragma unroll
            for (int k = 0; k < 16; ++k) r[k] = rw[k];   // 8x ds_read2_b32
            float f[32];
            #pragma unroll
            for (int k = 0; k < 16; ++k) {
                f[2 * k]     = __uint_as_float(r[k] << 16);
                f[2 * k + 1] = __uint_as_float(r[k] & 0xffff0000u);
            }
            #pragma unroll
            for (int j = 0; j < KW; ++j) {
                const int zi = i * KW + j;
                const unsigned int dw = zp[zi >> 1];
                const float w = __uint_as_float((zi & 1) ? (dw & 0xffff0000u)
                                                         : (dw << 16));
                #pragma unroll
                for (int c = 0; c < OW; ++c)
                    acc[c] = fmaf(f[c + j], w, acc[c]);
            }
        }

        // Contiguous 100 B per lane.
        float* __restrict__ og =
            out + (size_t)(base_slice + sl) * (OH * OW) + oy * OW;
        #pragma unroll
        for (int c = 0; c < OW; ++c) og[c] = acc[c] * 0.001f;
    }
}

extern "C" void kernel_launch(void* const* d_in, const int* in_sizes, int n_in,
                              void* d_out, int out_size, void* d_ws, size_t ws_size,
                              hipStream_t stream) {
    const float* z = (const float*)d_in[0];   // (64,256,7,7)
    const float* x = (const float*)d_in[1];   // (64,256,31,31)
    float* out = (float*)d_out;               // (64,256,25,25)
    const int nblk = (NSLICE + SPB - 1) / SPB;   // 3277
    xcorr_dw_kernel<<<dim3(nblk), dim3(THREADS), 0, stream>>>(z, x, out);
}

// Round 4
// 124.124 us; speedup vs baseline: 1.0707x; 1.0707x over previous
//
#include <hip/hip_runtime.h>

// Depthwise cross-correlation: z (64,256,7,7) over x (64,256,31,31) VALID
// -> out (64,256,25,25), scaled 0.001.
//
// Round 4: round-3 was throttled by store scatter (each wave's store instr
// touched 64 cachelines -> ~1600 L2 write transactions/wave ~= 17 us/CU) on
// top of 4-waves/SIMD occupancy (VGPR 104). Fixes:
//  - outputs staged through LDS (aliasing the dead x buffer, two 1600-dword
//    chunks), then block-wide flat coalesced stores (4 lines/instr).
//  - z kept in LDS as f32, read as broadcast ds_read in-loop: -25 VGPR
//    (no zp[25] cache), -49 extract VALU ops. VGPR ~80 -> 6 waves/SIMD.
// Compute core unchanged: thread = (slice, out-row), 16 aligned LDS dwords
// per kernel row (bf16 x, stride 34) feed 175 independent FMAs.

#define KH 7
#define KW 7
#define XH 31
#define XW 31
#define OH 25
#define OW 25
#define NSLICE (64 * 256)
#define SPB 5
#define THREADS 128
#define SEL 34                    // bf16 elements per padded LDS row (even)
#define XSLICE_E (XH * SEL)       // 1054 bf16 els per slice
#define XSLICE_W (XSLICE_E / 2)   // 527 dwords per slice
#define ROW_W (SEL / 2)           // 17 dwords per row
#define SMEM_W (SPB * XSLICE_W)   // 2635 dwords (10540 B)
#define CHUNK 1600                // out-stage chunk (64*25: never splits a thread's row)

__global__ __launch_bounds__(THREADS)
void xcorr_dw_kernel(const float* __restrict__ z,
                     const float* __restrict__ x,
                     float* __restrict__ out) {
    const int tid = threadIdx.x;
    const int base_slice = blockIdx.x * SPB;
    const int nsl = min(SPB, NSLICE - base_slice);

    __shared__ float smem[SMEM_W];       // x (bf16 view) during compute; out-stage after
    __shared__ float zs[SPB * KH * KW];  // 245 f32
    unsigned short* xs = (unsigned short*)smem;

    const float* __restrict__ xg = x + (size_t)base_slice * (XH * XW);
    const float* __restrict__ zg = z + (size_t)base_slice * (KH * KW);

    // ---- Stage x as bf16 (round-half-up): el = idx + 3*(idx/31) maps compact
    // global rows onto stride-34 LDS rows (31*34 = 1054, continuous per slice).
    const int nx = nsl * (XH * XW);
    for (int idx = tid; idx < nx; idx += THREADS) {
        const int row = idx / XW;                 // magic-mul div
        const int el  = idx + 3 * row;
        const unsigned int u = __float_as_uint(xg[idx]);
        xs[el] = (unsigned short)((u + 0x8000u) >> 16);
    }
    // ---- Stage z as f32, layout identical to global: direct coalesced copy.
    const int nz = nsl * (KH * KW);
    for (int t = tid; t < nz; t += THREADS) zs[t] = zg[t];
    __syncthreads();

    // ---- Compute: thread -> (slice, output row). 125 active lanes.
    const int sl = tid / 25;          // 0..5 (5 => lanes 125..127 idle)
    const int oy = tid - sl * 25;
    const bool active = (sl < nsl);

    float acc[OW] = {};
    if (active) {
        const unsigned int* __restrict__ xw =
            (const unsigned int*)xs + sl * XSLICE_W;
        const float* __restrict__ zrow = zs + sl * (KH * KW);
        #pragma unroll
        for (int i = 0; i < KH; ++i) {
            const unsigned int* __restrict__ rw = xw + (oy + i) * ROW_W;
            unsigned int r[16];
            #pragma unroll
            for (int k = 0; k < 16; ++k) r[k] = rw[k];   // 8x ds_read2_b32
            float f[32];
            #pragma unroll
            for (int k = 0; k < 16; ++k) {
                f[2 * k]     = __uint_as_float(r[k] << 16);
                f[2 * k + 1] = __uint_as_float(r[k] & 0xffff0000u);
            }
            #pragma unroll
            for (int j = 0; j < KW; ++j) {
                const float w = zrow[i * KW + j];        // broadcast ds_read
                #pragma unroll
                for (int c = 0; c < OW; ++c)
                    acc[c] = fmaf(f[c + j], w, acc[c]);
            }
        }
    }
    __syncthreads();   // all xs/zs reads done; smem reusable as out-stage

    // ---- Store: stage accs in LDS (write banks stride 25, <=2-way), then
    // block-flat coalesced global stores (64 consecutive dwords per instr).
    const int n_out = nsl * (OH * OW);
    const int fbase = sl * (OH * OW) + oy * OW;   // multiple of 25
    float* __restrict__ ogb = out + (size_t)base_slice * (OH * OW);
    #pragma unroll
    for (int c0 = 0; c0 < 2; ++c0) {
        const int lo = c0 * CHUNK;
        if (active && fbase >= lo && fbase < lo + CHUNK) {
            #pragma unroll
            for (int k = 0; k < OW; ++k)
                smem[fbase - lo + k] = acc[k] * 0.001f;
        }
        __syncthreads();
        const int nd = min(CHUNK, n_out - lo);
        for (int d = tid; d < nd; d += THREADS)
            ogb[lo + d] = smem[d];
        if (c0 == 0) __syncthreads();
    }
}

extern "C" void kernel_launch(void* const* d_in, const int* in_sizes, int n_in,
                              void* d_out, int out_size, void* d_ws, size_t ws_size,
                              hipStream_t stream) {
    const float* z = (const float*)d_in[0];   // (64,256,7,7)
    const float* x = (const float*)d_in[1];   // (64,256,31,31)
    float* out = (float*)d_out;               // (64,256,25,25)
    const int nblk = (NSLICE + SPB - 1) / SPB;   // 3277
    xcorr_dw_kernel<<<dim3(nblk), dim3(THREADS), 0, stream>>>(z, x, out);
}